// Round 1
// baseline (80.305 us; speedup 1.0000x reference)
//
#include <hip/hip_runtime.h>

#define BLOCK 256
#define GRID 2048

__global__ __launch_bounds__(BLOCK) void fd_partial(
    const float4* __restrict__ src4,
    const float4* __restrict__ tgt4,
    const float*  __restrict__ src,
    const float*  __restrict__ tgt,
    float* __restrict__ partials,
    int n4, int rem, long long n)
{
    const int tid    = blockIdx.x * blockDim.x + threadIdx.x;
    const int stride = gridDim.x * blockDim.x;

    float acc = 0.0f;
    for (int i = tid; i < n4; i += stride) {
        const float4 b4 = src4[i];   // source
        const float4 a4 = tgt4[i];   // target
        {
            float a = a4.x, b = b4.x;
            float d = (a < 0.0f && b < 0.0f) ? fmaf(-2.0f, a, b) : b;
            acc = fmaf(d, d, acc);
        }
        {
            float a = a4.y, b = b4.y;
            float d = (a < 0.0f && b < 0.0f) ? fmaf(-2.0f, a, b) : b;
            acc = fmaf(d, d, acc);
        }
        {
            float a = a4.z, b = b4.z;
            float d = (a < 0.0f && b < 0.0f) ? fmaf(-2.0f, a, b) : b;
            acc = fmaf(d, d, acc);
        }
        {
            float a = a4.w, b = b4.w;
            float d = (a < 0.0f && b < 0.0f) ? fmaf(-2.0f, a, b) : b;
            acc = fmaf(d, d, acc);
        }
    }
    // scalar tail (n not multiple of 4) handled by global thread 0
    if (tid == 0 && rem) {
        for (long long i = n - rem; i < n; ++i) {
            float a = tgt[i], b = src[i];
            float d = (a < 0.0f && b < 0.0f) ? fmaf(-2.0f, a, b) : b;
            acc = fmaf(d, d, acc);
        }
    }

    // wave-64 butterfly reduce
    #pragma unroll
    for (int off = 32; off; off >>= 1)
        acc += __shfl_down(acc, off, 64);

    __shared__ float lds[BLOCK / 64];
    const int lane = threadIdx.x & 63;
    const int wave = threadIdx.x >> 6;
    if (lane == 0) lds[wave] = acc;
    __syncthreads();
    if (threadIdx.x == 0) {
        float s = lds[0] + lds[1] + lds[2] + lds[3];
        partials[blockIdx.x] = s;
    }
}

__global__ __launch_bounds__(BLOCK) void fd_final(
    const float* __restrict__ partials,
    float* __restrict__ out,
    int nblocks, float invN)
{
    float acc = 0.0f;
    for (int i = threadIdx.x; i < nblocks; i += BLOCK)
        acc += partials[i];

    #pragma unroll
    for (int off = 32; off; off >>= 1)
        acc += __shfl_down(acc, off, 64);

    __shared__ float lds[BLOCK / 64];
    const int lane = threadIdx.x & 63;
    const int wave = threadIdx.x >> 6;
    if (lane == 0) lds[wave] = acc;
    __syncthreads();
    if (threadIdx.x == 0)
        out[0] = (lds[0] + lds[1] + lds[2] + lds[3]) * invN;
}

extern "C" void kernel_launch(void* const* d_in, const int* in_sizes, int n_in,
                              void* d_out, int out_size, void* d_ws, size_t ws_size,
                              hipStream_t stream)
{
    const float* src = (const float*)d_in[0];  // source -> b
    const float* tgt = (const float*)d_in[1];  // target -> a
    float* out      = (float*)d_out;
    float* partials = (float*)d_ws;            // GRID floats of scratch

    const long long n = (long long)in_sizes[0];
    const int n4  = (int)(n >> 2);
    const int rem = (int)(n & 3);

    fd_partial<<<GRID, BLOCK, 0, stream>>>(
        (const float4*)src, (const float4*)tgt, src, tgt, partials, n4, rem, n);
    fd_final<<<1, BLOCK, 0, stream>>>(partials, out, GRID, 1.0f / (float)n);
}